// Round 1
// baseline (470.459 us; speedup 1.0000x reference)
//
#include <hip/hip_runtime.h>
#include <math.h>

#define BB 8
#define HH 640
#define WW 640
#define HWN (HH*WW)
#define CC 10
#define KCH 5
#define DD 4
#define LL 16
#define NBINS 256

// ws layout (float offsets)
#define WS_OHEM      0                       // BB*8: [n_pos, s_pos, s_pos2, n_neg, s_neg2, ...]
#define WS_HCNT      64                      // BB*NBINS
#define WS_HS2       (WS_HCNT + BB*NBINS)    // BB*NBINS
#define WS_KERN      (WS_HS2 + BB*NBINS)     // 40*3
#define WS_ECNT      (WS_KERN + 120)         // BB*LL
#define WS_ESUM      (WS_ECNT + BB*LL)       // BB*LL*DD
#define WS_ECV       (WS_ESUM + BB*LL*DD)    // BB*LL
#define WS_ZERO_END  (WS_ECV + BB*LL)        // zero [0, WS_ZERO_END)
#define WS_MEANS     WS_ZERO_END             // BB*LL*DD (written before read)
#define WS_MISC      (WS_MEANS + BB*LL*DD)   // BB*4: nf, ld, lr, act

__device__ __forceinline__ float sigm(float x) { return 1.f / (1.f + expf(-x)); }

// Kernel 1: 9x9 max-dilation of pred[:,0] logits (separable, LDS-tiled),
// sigmoid, then per-batch OHEM stats (pos/neg counts+sums + neg histogram).
__global__ __launch_bounds__(256) void k_dil_stats(
    const float* __restrict__ pred, const float* __restrict__ gt_t,
    const float* __restrict__ tm, float* __restrict__ ws)
{
    __shared__ float tile[40][41];
    __shared__ float hmax[40][33];
    __shared__ float hcnt[NBINS];
    __shared__ float hs2[NBINS];
    __shared__ float red[8];
    const int b  = blockIdx.z;
    const int x0 = blockIdx.x * 32 - 4;
    const int y0 = blockIdx.y * 32 - 4;
    const int tid = threadIdx.y * 32 + threadIdx.x;
    const float* p0 = pred + (size_t)b * CC * HWN;   // channel 0

    for (int i = tid; i < NBINS; i += 256) { hcnt[i] = 0.f; hs2[i] = 0.f; }
    if (tid < 8) red[tid] = 0.f;

    for (int i = tid; i < 40 * 40; i += 256) {
        int r = i / 40, c = i - r * 40;
        int gy = y0 + r, gx = x0 + c;
        float v = -INFINITY;
        if (gy >= 0 && gy < HH && gx >= 0 && gx < WW) v = p0[gy * WW + gx];
        tile[r][c] = v;
    }
    __syncthreads();
    for (int i = tid; i < 40 * 32; i += 256) {
        int r = i >> 5, c = i & 31;
        float m = tile[r][c];
        #pragma unroll
        for (int k = 1; k < 9; k++) m = fmaxf(m, tile[r][c + k]);
        hmax[r][c] = m;
    }
    __syncthreads();

    float c_pos = 0.f, s_pos = 0.f, s_pos2 = 0.f, c_neg = 0.f, s_neg2 = 0.f;
    const int cx = threadIdx.x;
    for (int ry = threadIdx.y; ry < 32; ry += 8) {
        float m = hmax[ry][cx];
        #pragma unroll
        for (int k = 1; k < 9; k++) m = fmaxf(m, hmax[ry + k][cx]);
        float dil = sigm(m);
        int gy = y0 + 4 + ry, gx = x0 + 4 + cx;
        size_t gidx = (size_t)b * HWN + (size_t)gy * WW + gx;
        float g = gt_t[gidx], mv = tm[gidx];
        if (mv > 0.5f) {
            if (g > 0.5f) { c_pos += 1.f; s_pos += dil; s_pos2 += dil * dil; }
            else {
                c_neg += 1.f; s_neg2 += dil * dil;
                int bin = (int)((m + 8.f) * 16.f);
                bin = min(max(bin, 0), NBINS - 1);
                atomicAdd(&hcnt[bin], 1.f);
                atomicAdd(&hs2[bin], dil * dil);
            }
        }
    }
    #pragma unroll
    for (int o = 32; o > 0; o >>= 1) {
        c_pos  += __shfl_down(c_pos, o);
        s_pos  += __shfl_down(s_pos, o);
        s_pos2 += __shfl_down(s_pos2, o);
        c_neg  += __shfl_down(c_neg, o);
        s_neg2 += __shfl_down(s_neg2, o);
    }
    if ((tid & 63) == 0) {
        atomicAdd(&red[0], c_pos);  atomicAdd(&red[1], s_pos);
        atomicAdd(&red[2], s_pos2); atomicAdd(&red[3], c_neg);
        atomicAdd(&red[4], s_neg2);
    }
    __syncthreads();
    float* oh = ws + WS_OHEM + b * 8;
    if (tid < 5) atomicAdd(&oh[tid], red[tid]);
    float* gh_c = ws + WS_HCNT + b * NBINS;
    float* gh_s = ws + WS_HS2  + b * NBINS;
    for (int i = tid; i < NBINS; i += 256) {
        if (hcnt[i] != 0.f) { atomicAdd(&gh_c[i], hcnt[i]); atomicAdd(&gh_s[i], hs2[i]); }
    }
}

// Kernel 2: per-(b,k) dice partial sums over 5 kernel channels.
__global__ __launch_bounds__(256) void k_kern_dice(
    const float* __restrict__ pred, const float* __restrict__ gtk,
    const float* __restrict__ tm, float* __restrict__ ws)
{
    const int row = blockIdx.y;            // 0..39
    const int b = row / KCH, k = row - b * KCH;
    const float* p = pred + ((size_t)b * CC + 1 + k) * HWN;
    const float* g = gtk + (size_t)row * HWN;
    const float* m = tm + (size_t)b * HWN;
    const int start = blockIdx.x * 4096;
    float i1 = 0.f, i2 = 0.f, i3 = 0.f;
    for (int j = start + threadIdx.x; j < start + 4096; j += 256) {
        float pv = sigm(p[j]);
        float gv = g[j], mv = m[j];
        i1 += pv * gv * mv;
        i2 += pv * pv * mv;
        i3 += gv * mv;
    }
    #pragma unroll
    for (int o = 32; o > 0; o >>= 1) {
        i1 += __shfl_down(i1, o); i2 += __shfl_down(i2, o); i3 += __shfl_down(i3, o);
    }
    __shared__ float sred[12];
    int wv = threadIdx.x >> 6;
    if ((threadIdx.x & 63) == 0) { sred[wv*3] = i1; sred[wv*3+1] = i2; sred[wv*3+2] = i3; }
    __syncthreads();
    if (threadIdx.x == 0) {
        float a = 0.f, bb = 0.f, c = 0.f;
        for (int w = 0; w < 4; w++) { a += sred[w*3]; bb += sred[w*3+1]; c += sred[w*3+2]; }
        float* kk = ws + WS_KERN + row * 3;
        atomicAdd(&kk[0], a); atomicAdd(&kk[1], bb); atomicAdd(&kk[2], c);
    }
}

// Kernel 3: embedding pass 1 — per-(batch,label) counts and feature sums.
__global__ __launch_bounds__(256) void k_emb1(
    const float* __restrict__ pred, const int* __restrict__ inst,
    const float* __restrict__ tm, float* __restrict__ ws)
{
    const int b = blockIdx.y;
    __shared__ float cnt[LL];
    __shared__ float sums[LL * DD];
    const int tid = threadIdx.x;
    if (tid < LL) cnt[tid] = 0.f;
    if (tid < LL * DD) sums[tid] = 0.f;
    __syncthreads();
    const float* e0 = pred + ((size_t)b * CC + 6) * HWN;
    const float* tmb = tm + (size_t)b * HWN;
    const int* ib = inst + (size_t)b * HWN;
    const int start = blockIdx.x * 4096;
    for (int j = start + tid; j < start + 4096; j += 256) {
        if (tmb[j] > 0.f) {
            int l = ib[j];
            atomicAdd(&cnt[l], 1.f);
            atomicAdd(&sums[l * DD + 0], e0[j]);
            atomicAdd(&sums[l * DD + 1], e0[HWN + j]);
            atomicAdd(&sums[l * DD + 2], e0[2 * HWN + j]);
            atomicAdd(&sums[l * DD + 3], e0[3 * HWN + j]);
        }
    }
    __syncthreads();
    if (tid < LL) atomicAdd(&ws[WS_ECNT + b * LL + tid], cnt[tid]);
    if (tid < LL * DD) atomicAdd(&ws[WS_ESUM + b * LL * DD + tid], sums[tid]);
}

// Kernel 4: per-batch means, pairwise ld, lr (tiny; one block per batch).
__global__ __launch_bounds__(128) void k_emb_means(float* __restrict__ ws)
{
    const int b = blockIdx.x;
    __shared__ float mn[LL][DD];
    __shared__ float pres[LL];
    __shared__ float redp[128];
    __shared__ float redr[LL];
    const int tid = threadIdx.x;
    if (tid < LL) {
        float c = ws[WS_ECNT + b * LL + tid];
        float inv = 1.f / fmaxf(c, 1.f);
        #pragma unroll
        for (int d = 0; d < DD; d++) {
            float mv = ws[WS_ESUM + b * LL * DD + tid * DD + d] * inv;
            mn[tid][d] = mv;
            ws[WS_MEANS + b * LL * DD + tid * DD + d] = mv;
        }
        pres[tid] = (c > 0.f) ? 1.f : 0.f;
    }
    __syncthreads();
    float ldv = 0.f;
    if (tid < 120) {
        int idx = tid, ii = 0;
        while (idx >= (LL - 1 - ii)) { idx -= (LL - 1 - ii); ii++; }
        int jj = ii + 1 + idx;
        float s = 1e-12f;
        #pragma unroll
        for (int d = 0; d < DD; d++) { float df = mn[ii][d] - mn[jj][d]; s += df * df; }
        float pd = sqrtf(s);
        float t = fmaxf(3.0f - pd, 0.f);   // 2*DELTA_D = 3.0
        ldv = (pres[ii] > 0.f && pres[jj] > 0.f) ? t * t : 0.f;
    }
    redp[tid] = ldv;
    float lrv = 0.f;
    if (tid < LL && pres[tid] > 0.f) {
        float s = 1e-12f;
        #pragma unroll
        for (int d = 0; d < DD; d++) s += mn[tid][d] * mn[tid][d];
        lrv = sqrtf(s);
    }
    if (tid < LL) redr[tid] = lrv;
    __syncthreads();
    if (tid == 0) {
        float nf = 0.f;
        for (int i = 0; i < LL; i++) nf += pres[i];
        float ld = 0.f;
        for (int i = 0; i < 120; i++) ld += redp[i];
        float lr = 0.f;
        for (int i = 0; i < LL; i++) lr += redr[i];
        float act = (nf > 1.f) ? 1.f : 0.f;
        ld = act * ld / fmaxf(nf * (nf - 1.f), 1.f);
        lr = act * lr / fmaxf(nf, 1.f);
        ws[WS_MISC + b * 4 + 0] = nf;
        ws[WS_MISC + b * 4 + 1] = ld;
        ws[WS_MISC + b * 4 + 2] = lr;
        ws[WS_MISC + b * 4 + 3] = act;
    }
}

// Kernel 5: embedding pass 2 — per-(batch,label) variance term cv sums.
__global__ __launch_bounds__(256) void k_emb2(
    const float* __restrict__ pred, const int* __restrict__ inst,
    const float* __restrict__ tm, float* __restrict__ ws)
{
    const int b = blockIdx.y;
    __shared__ float cv[LL];
    __shared__ float mn[LL * DD];
    const int tid = threadIdx.x;
    if (tid < LL) cv[tid] = 0.f;
    if (tid < LL * DD) mn[tid] = ws[WS_MEANS + b * LL * DD + tid];
    __syncthreads();
    const float* e0 = pred + ((size_t)b * CC + 6) * HWN;
    const float* tmb = tm + (size_t)b * HWN;
    const int* ib = inst + (size_t)b * HWN;
    const int start = blockIdx.x * 4096;
    for (int j = start + tid; j < start + 4096; j += 256) {
        if (tmb[j] > 0.f) {
            int l = ib[j];
            float d0 = e0[j]           - mn[l * DD + 0];
            float d1 = e0[HWN + j]     - mn[l * DD + 1];
            float d2 = e0[2 * HWN + j] - mn[l * DD + 2];
            float d3 = e0[3 * HWN + j] - mn[l * DD + 3];
            float dd = sqrtf(d0*d0 + d1*d1 + d2*d2 + d3*d3 + 1e-12f);
            float t = fmaxf(dd - 0.5f, 0.f);   // DELTA_V = 0.5
            atomicAdd(&cv[l], t * t);
        }
    }
    __syncthreads();
    if (tid < LL) atomicAdd(&ws[WS_ECV + b * LL + tid], cv[tid]);
}

// Kernel 6: final combine → 4 scalars.
__global__ __launch_bounds__(64) void k_final(const float* __restrict__ ws, float* __restrict__ out)
{
    __shared__ float s_text[BB];
    __shared__ float s_kern[40];
    __shared__ float s_lv[BB], s_ld[BB], s_lr[BB];
    const int tid = threadIdx.x;
    if (tid < BB) {
        const float* o = ws + WS_OHEM + tid * 8;
        float npos = o[0], spos = o[1], spos2 = o[2], nnegt = o[3], sneg2t = o[4];
        float nneg = fminf(3.f * npos, nnegt);
        float ssel;
        if (nneg >= nnegt) ssel = sneg2t;       // all negatives selected (exact path)
        else {
            const float* hc = ws + WS_HCNT + tid * NBINS;
            const float* hs = ws + WS_HS2  + tid * NBINS;
            float acc = 0.f; ssel = 0.f;
            for (int i = NBINS - 1; i >= 0; i--) {
                float c = hc[i];
                if (c <= 0.f) continue;
                if (acc + c <= nneg) { ssel += hs[i]; acc += c; }
                else { float r = nneg - acc; ssel += r * (hs[i] / c); break; }
            }
        }
        float uni = spos2 + ssel + npos + 1e-6f;
        s_text[tid] = 1.f - 2.f * spos / uni;

        float nf  = ws[WS_MISC + tid * 4 + 0];
        float act = ws[WS_MISC + tid * 4 + 3];
        float lv = 0.f;
        for (int l = 0; l < LL; l++) {
            float c = ws[WS_ECNT + tid * LL + l];
            if (c > 0.f) lv += ws[WS_ECV + tid * LL + l] / fmaxf(c, 1.f);
        }
        s_lv[tid] = act * lv / fmaxf(nf, 1.f);
        s_ld[tid] = ws[WS_MISC + tid * 4 + 1];
        s_lr[tid] = ws[WS_MISC + tid * 4 + 2];
    }
    if (tid < 40) {
        const float* kk = ws + WS_KERN + tid * 3;
        s_kern[tid] = 1.f - 2.f * kk[0] / (kk[1] + kk[2] + 1e-6f);
    }
    __syncthreads();
    if (tid == 0) {
        float lt = 0.f; for (int i = 0; i < BB; i++) lt += s_text[i]; lt /= (float)BB;
        float lk = 0.f; for (int i = 0; i < 40; i++) lk += s_kern[i]; lk /= 40.f;
        float lvs = 0.f, lds_ = 0.f, lrs = 0.f;
        for (int i = 0; i < BB; i++) { lvs += s_lv[i]; lds_ += s_ld[i]; lrs += s_lr[i]; }
        float lemb = 0.25f * (lvs + lds_ + 0.001f * (lrs / (float)BB));
        out[0] = lk + 0.5f * lt + lemb;
        out[1] = lt;
        out[2] = lk;
        out[3] = lemb;
    }
}

extern "C" void kernel_launch(void* const* d_in, const int* in_sizes, int n_in,
                              void* d_out, int out_size, void* d_ws, size_t ws_size,
                              hipStream_t stream)
{
    (void)in_sizes; (void)n_in; (void)out_size; (void)ws_size;
    const float* pred = (const float*)d_in[0];
    const float* gt_t = (const float*)d_in[1];
    const float* gtk  = (const float*)d_in[2];
    const float* tm   = (const float*)d_in[3];
    const int*   inst = (const int*)d_in[4];
    float* out = (float*)d_out;
    float* ws  = (float*)d_ws;

    hipMemsetAsync(d_ws, 0, WS_ZERO_END * sizeof(float), stream);

    dim3 g1(WW / 32, HH / 32, BB), b1(32, 8, 1);
    k_dil_stats<<<g1, b1, 0, stream>>>(pred, gt_t, tm, ws);
    k_kern_dice<<<dim3(100, 40), 256, 0, stream>>>(pred, gtk, tm, ws);
    k_emb1<<<dim3(100, BB), 256, 0, stream>>>(pred, inst, tm, ws);
    k_emb_means<<<BB, 128, 0, stream>>>(ws);
    k_emb2<<<dim3(100, BB), 256, 0, stream>>>(pred, inst, tm, ws);
    k_final<<<1, 64, 0, stream>>>(ws, out);
}

// Round 2
// 349.074 us; speedup vs baseline: 1.3477x; 1.3477x over previous
//
#include <hip/hip_runtime.h>
#include <math.h>

#define BB 8
#define HH 640
#define WW 640
#define HWN (HH*WW)
#define CC 10
#define KCH 5
#define DD 4
#define LL 16
#define NBINS 256

// ws layout (float offsets)
#define WS_OHEM      0                       // BB*8: [n_pos, s_pos, s_pos2, n_neg, s_neg2, ...]
#define WS_HCNT      64                      // BB*NBINS
#define WS_HS2       (WS_HCNT + BB*NBINS)    // BB*NBINS
#define WS_KERN      (WS_HS2 + BB*NBINS)     // 40*3
#define WS_ECNT      (WS_KERN + 120)         // BB*LL
#define WS_ESUM      (WS_ECNT + BB*LL)       // BB*LL*DD
#define WS_ECV       (WS_ESUM + BB*LL*DD)    // BB*LL
#define WS_ZERO_END  (WS_ECV + BB*LL)        // zero [0, WS_ZERO_END)
#define WS_MEANS     WS_ZERO_END             // BB*LL*DD (written before read)
#define WS_MISC      (WS_MEANS + BB*LL*DD)   // BB*4: nf, ld, lr, act

__device__ __forceinline__ float sigm(float x) { return 1.f / (1.f + expf(-x)); }

__device__ __forceinline__ float wave_red(float v) {
    #pragma unroll
    for (int o = 32; o > 0; o >>= 1) v += __shfl_down(v, o);
    return v;
}

// Kernel 1: 9x9 max-dilation of pred[:,0] logits (separable, LDS-tiled),
// sigmoid, then per-batch OHEM stats (pos/neg counts+sums + neg histogram).
__global__ __launch_bounds__(256) void k_dil_stats(
    const float* __restrict__ pred, const float* __restrict__ gt_t,
    const float* __restrict__ tm, float* __restrict__ ws)
{
    __shared__ float tile[40][41];
    __shared__ float hmax[40][33];
    __shared__ float hcnt[NBINS];
    __shared__ float hs2[NBINS];
    __shared__ float red[8];
    const int b  = blockIdx.z;
    const int x0 = blockIdx.x * 32 - 4;
    const int y0 = blockIdx.y * 32 - 4;
    const int tid = threadIdx.y * 32 + threadIdx.x;
    const float* p0 = pred + (size_t)b * CC * HWN;   // channel 0

    for (int i = tid; i < NBINS; i += 256) { hcnt[i] = 0.f; hs2[i] = 0.f; }
    if (tid < 8) red[tid] = 0.f;

    for (int i = tid; i < 40 * 40; i += 256) {
        int r = i / 40, c = i - r * 40;
        int gy = y0 + r, gx = x0 + c;
        float v = -INFINITY;
        if (gy >= 0 && gy < HH && gx >= 0 && gx < WW) v = p0[gy * WW + gx];
        tile[r][c] = v;
    }
    __syncthreads();
    for (int i = tid; i < 40 * 32; i += 256) {
        int r = i >> 5, c = i & 31;
        float m = tile[r][c];
        #pragma unroll
        for (int k = 1; k < 9; k++) m = fmaxf(m, tile[r][c + k]);
        hmax[r][c] = m;
    }
    __syncthreads();

    float c_pos = 0.f, s_pos = 0.f, s_pos2 = 0.f, c_neg = 0.f, s_neg2 = 0.f;
    const int cx = threadIdx.x;
    for (int ry = threadIdx.y; ry < 32; ry += 8) {
        float m = hmax[ry][cx];
        #pragma unroll
        for (int k = 1; k < 9; k++) m = fmaxf(m, hmax[ry + k][cx]);
        float dil = sigm(m);
        int gy = y0 + 4 + ry, gx = x0 + 4 + cx;
        size_t gidx = (size_t)b * HWN + (size_t)gy * WW + gx;
        float g = gt_t[gidx], mv = tm[gidx];
        if (mv > 0.5f) {
            if (g > 0.5f) { c_pos += 1.f; s_pos += dil; s_pos2 += dil * dil; }
            else {
                c_neg += 1.f; s_neg2 += dil * dil;
                int bin = (int)((m + 8.f) * 16.f);
                bin = min(max(bin, 0), NBINS - 1);
                atomicAdd(&hcnt[bin], 1.f);
                atomicAdd(&hs2[bin], dil * dil);
            }
        }
    }
    c_pos = wave_red(c_pos); s_pos = wave_red(s_pos); s_pos2 = wave_red(s_pos2);
    c_neg = wave_red(c_neg); s_neg2 = wave_red(s_neg2);
    if ((tid & 63) == 0) {
        atomicAdd(&red[0], c_pos);  atomicAdd(&red[1], s_pos);
        atomicAdd(&red[2], s_pos2); atomicAdd(&red[3], c_neg);
        atomicAdd(&red[4], s_neg2);
    }
    __syncthreads();
    float* oh = ws + WS_OHEM + b * 8;
    if (tid < 5) atomicAdd(&oh[tid], red[tid]);
    float* gh_c = ws + WS_HCNT + b * NBINS;
    float* gh_s = ws + WS_HS2  + b * NBINS;
    for (int i = tid; i < NBINS; i += 256) {
        if (hcnt[i] != 0.f) { atomicAdd(&gh_c[i], hcnt[i]); atomicAdd(&gh_s[i], hs2[i]); }
    }
}

// Kernel 2: per-(b,k) dice partial sums over 5 kernel channels. float4 loads.
__global__ __launch_bounds__(256) void k_kern_dice(
    const float* __restrict__ pred, const float* __restrict__ gtk,
    const float* __restrict__ tm, float* __restrict__ ws)
{
    const int row = blockIdx.y;            // 0..39
    const int b = row / KCH, k = row - b * KCH;
    const float4* p = (const float4*)(pred + ((size_t)b * CC + 1 + k) * HWN);
    const float4* g = (const float4*)(gtk + (size_t)row * HWN);
    const float4* m = (const float4*)(tm + (size_t)b * HWN);
    const int nv = HWN / 4;
    float i1 = 0.f, i2 = 0.f, i3 = 0.f;
    for (int j = blockIdx.x * 256 + threadIdx.x; j < nv; j += gridDim.x * 256) {
        float4 pv = p[j], gv = g[j], mv = m[j];
        float s0 = sigm(pv.x), s1 = sigm(pv.y), s2 = sigm(pv.z), s3 = sigm(pv.w);
        i1 += s0*gv.x*mv.x + s1*gv.y*mv.y + s2*gv.z*mv.z + s3*gv.w*mv.w;
        i2 += s0*s0*mv.x + s1*s1*mv.y + s2*s2*mv.z + s3*s3*mv.w;
        i3 += gv.x*mv.x + gv.y*mv.y + gv.z*mv.z + gv.w*mv.w;
    }
    i1 = wave_red(i1); i2 = wave_red(i2); i3 = wave_red(i3);
    __shared__ float sred[12];
    int wv = threadIdx.x >> 6;
    if ((threadIdx.x & 63) == 0) { sred[wv*3] = i1; sred[wv*3+1] = i2; sred[wv*3+2] = i3; }
    __syncthreads();
    if (threadIdx.x == 0) {
        float a = 0.f, bb = 0.f, c = 0.f;
        for (int w = 0; w < 4; w++) { a += sred[w*3]; bb += sred[w*3+1]; c += sred[w*3+2]; }
        float* kk = ws + WS_KERN + row * 3;
        atomicAdd(&kk[0], a); atomicAdd(&kk[1], bb); atomicAdd(&kk[2], c);
    }
}

// Kernel 3: embedding pass 1 — register-privatized per-label count/sums.
// No per-pixel atomics: 16x5 register accumulators + compare-select FMA.
__global__ __launch_bounds__(256) void k_emb1(
    const float* __restrict__ pred, const int* __restrict__ inst,
    const float* __restrict__ tm, float* __restrict__ ws)
{
    const int b = blockIdx.y;
    const int tid = threadIdx.x;
    const float* e0 = pred + ((size_t)b * CC + 6) * HWN;
    const float4* v0p = (const float4*)e0;
    const float4* v1p = (const float4*)(e0 + HWN);
    const float4* v2p = (const float4*)(e0 + 2 * HWN);
    const float4* v3p = (const float4*)(e0 + 3 * HWN);
    const float4* tmv = (const float4*)(tm + (size_t)b * HWN);
    const int4*   iv  = (const int4*)(inst + (size_t)b * HWN);

    float cnt[LL], s0[LL], s1[LL], s2[LL], s3[LL];
    #pragma unroll
    for (int l = 0; l < LL; l++) { cnt[l]=0.f; s0[l]=0.f; s1[l]=0.f; s2[l]=0.f; s3[l]=0.f; }

    const int nv = HWN / 4;
    for (int j = blockIdx.x * 256 + tid; j < nv; j += gridDim.x * 256) {
        float4 a0 = v0p[j], a1 = v1p[j], a2 = v2p[j], a3 = v3p[j];
        float4 t = tmv[j];
        int4 li = iv[j];
        int lab0 = (t.x > 0.f) ? li.x : LL;
        int lab1 = (t.y > 0.f) ? li.y : LL;
        int lab2 = (t.z > 0.f) ? li.z : LL;
        int lab3 = (t.w > 0.f) ? li.w : LL;
        #pragma unroll
        for (int l = 0; l < LL; l++) {
            float m0 = (lab0 == l) ? 1.f : 0.f;
            float m1 = (lab1 == l) ? 1.f : 0.f;
            float m2 = (lab2 == l) ? 1.f : 0.f;
            float m3 = (lab3 == l) ? 1.f : 0.f;
            cnt[l] += (m0 + m1) + (m2 + m3);
            s0[l] += m0*a0.x + m1*a0.y + m2*a0.z + m3*a0.w;
            s1[l] += m0*a1.x + m1*a1.y + m2*a1.z + m3*a1.w;
            s2[l] += m0*a2.x + m1*a2.y + m2*a2.z + m3*a2.w;
            s3[l] += m0*a3.x + m1*a3.y + m2*a3.z + m3*a3.w;
        }
    }

    __shared__ float sred[4][80];
    const int wv = tid >> 6, ln = tid & 63;
    #pragma unroll
    for (int l = 0; l < LL; l++) {
        float r0 = wave_red(cnt[l]);
        float r1 = wave_red(s0[l]);
        float r2 = wave_red(s1[l]);
        float r3 = wave_red(s2[l]);
        float r4 = wave_red(s3[l]);
        if (ln == 0) {
            sred[wv][l*5+0] = r0; sred[wv][l*5+1] = r1; sred[wv][l*5+2] = r2;
            sred[wv][l*5+3] = r3; sred[wv][l*5+4] = r4;
        }
    }
    __syncthreads();
    if (tid < 80) {
        float s = sred[0][tid] + sred[1][tid] + sred[2][tid] + sred[3][tid];
        int l = tid / 5, c = tid - l * 5;
        if (c == 0) atomicAdd(&ws[WS_ECNT + b * LL + l], s);
        else        atomicAdd(&ws[WS_ESUM + b * LL * DD + l * DD + (c - 1)], s);
    }
}

// Kernel 4: per-batch means, pairwise ld, lr (tiny; one block per batch).
__global__ __launch_bounds__(128) void k_emb_means(float* __restrict__ ws)
{
    const int b = blockIdx.x;
    __shared__ float mn[LL][DD];
    __shared__ float pres[LL];
    __shared__ float redp[128];
    __shared__ float redr[LL];
    const int tid = threadIdx.x;
    if (tid < LL) {
        float c = ws[WS_ECNT + b * LL + tid];
        float inv = 1.f / fmaxf(c, 1.f);
        #pragma unroll
        for (int d = 0; d < DD; d++) {
            float mv = ws[WS_ESUM + b * LL * DD + tid * DD + d] * inv;
            mn[tid][d] = mv;
            ws[WS_MEANS + b * LL * DD + tid * DD + d] = mv;
        }
        pres[tid] = (c > 0.f) ? 1.f : 0.f;
    }
    __syncthreads();
    float ldv = 0.f;
    if (tid < 120) {
        int idx = tid, ii = 0;
        while (idx >= (LL - 1 - ii)) { idx -= (LL - 1 - ii); ii++; }
        int jj = ii + 1 + idx;
        float s = 1e-12f;
        #pragma unroll
        for (int d = 0; d < DD; d++) { float df = mn[ii][d] - mn[jj][d]; s += df * df; }
        float pd = sqrtf(s);
        float t = fmaxf(3.0f - pd, 0.f);   // 2*DELTA_D = 3.0
        ldv = (pres[ii] > 0.f && pres[jj] > 0.f) ? t * t : 0.f;
    }
    redp[tid] = ldv;
    float lrv = 0.f;
    if (tid < LL && pres[tid] > 0.f) {
        float s = 1e-12f;
        #pragma unroll
        for (int d = 0; d < DD; d++) s += mn[tid][d] * mn[tid][d];
        lrv = sqrtf(s);
    }
    if (tid < LL) redr[tid] = lrv;
    __syncthreads();
    if (tid == 0) {
        float nf = 0.f;
        for (int i = 0; i < LL; i++) nf += pres[i];
        float ld = 0.f;
        for (int i = 0; i < 120; i++) ld += redp[i];
        float lr = 0.f;
        for (int i = 0; i < LL; i++) lr += redr[i];
        float act = (nf > 1.f) ? 1.f : 0.f;
        ld = act * ld / fmaxf(nf * (nf - 1.f), 1.f);
        lr = act * lr / fmaxf(nf, 1.f);
        ws[WS_MISC + b * 4 + 0] = nf;
        ws[WS_MISC + b * 4 + 1] = ld;
        ws[WS_MISC + b * 4 + 2] = lr;
        ws[WS_MISC + b * 4 + 3] = act;
    }
}

// Kernel 5: embedding pass 2 — register-privatized cv accumulation.
__global__ __launch_bounds__(256) void k_emb2(
    const float* __restrict__ pred, const int* __restrict__ inst,
    const float* __restrict__ tm, float* __restrict__ ws)
{
    const int b = blockIdx.y;
    const int tid = threadIdx.x;
    __shared__ float mn[LL * DD];
    if (tid < LL * DD) mn[tid] = ws[WS_MEANS + b * LL * DD + tid];
    __syncthreads();

    const float* e0 = pred + ((size_t)b * CC + 6) * HWN;
    const float4* v0p = (const float4*)e0;
    const float4* v1p = (const float4*)(e0 + HWN);
    const float4* v2p = (const float4*)(e0 + 2 * HWN);
    const float4* v3p = (const float4*)(e0 + 3 * HWN);
    const float4* tmv = (const float4*)(tm + (size_t)b * HWN);
    const int4*   iv  = (const int4*)(inst + (size_t)b * HWN);

    float cv[LL];
    #pragma unroll
    for (int l = 0; l < LL; l++) cv[l] = 0.f;

    const int nv = HWN / 4;
    for (int j = blockIdx.x * 256 + tid; j < nv; j += gridDim.x * 256) {
        float4 a0 = v0p[j], a1 = v1p[j], a2 = v2p[j], a3 = v3p[j];
        float4 t = tmv[j];
        int4 li = iv[j];
        int lab[4];
        lab[0] = (t.x > 0.f) ? li.x : LL;
        lab[1] = (t.y > 0.f) ? li.y : LL;
        lab[2] = (t.z > 0.f) ? li.z : LL;
        lab[3] = (t.w > 0.f) ? li.w : LL;
        float ex[4] = {a0.x, a0.y, a0.z, a0.w};
        float ey[4] = {a1.x, a1.y, a1.z, a1.w};
        float ez[4] = {a2.x, a2.y, a2.z, a2.w};
        float ew[4] = {a3.x, a3.y, a3.z, a3.w};
        #pragma unroll
        for (int q = 0; q < 4; q++) {
            int l = lab[q];
            int lc = (l < LL) ? l : 0;           // safe LDS index; masked below
            float d0 = ex[q] - mn[lc * DD + 0];
            float d1 = ey[q] - mn[lc * DD + 1];
            float d2 = ez[q] - mn[lc * DD + 2];
            float d3 = ew[q] - mn[lc * DD + 3];
            float dd = sqrtf(d0*d0 + d1*d1 + d2*d2 + d3*d3 + 1e-12f);
            float tt = fmaxf(dd - 0.5f, 0.f);    // DELTA_V = 0.5
            float t2 = tt * tt;
            #pragma unroll
            for (int k = 0; k < LL; k++) {
                float m = (l == k) ? 1.f : 0.f;
                cv[k] += m * t2;
            }
        }
    }

    __shared__ float sred[4][LL];
    const int wv = tid >> 6, ln = tid & 63;
    #pragma unroll
    for (int l = 0; l < LL; l++) {
        float r = wave_red(cv[l]);
        if (ln == 0) sred[wv][l] = r;
    }
    __syncthreads();
    if (tid < LL) {
        float s = sred[0][tid] + sred[1][tid] + sred[2][tid] + sred[3][tid];
        atomicAdd(&ws[WS_ECV + b * LL + tid], s);
    }
}

// Kernel 6: final combine → 4 scalars.
__global__ __launch_bounds__(64) void k_final(const float* __restrict__ ws, float* __restrict__ out)
{
    __shared__ float s_text[BB];
    __shared__ float s_kern[40];
    __shared__ float s_lv[BB], s_ld[BB], s_lr[BB];
    const int tid = threadIdx.x;
    if (tid < BB) {
        const float* o = ws + WS_OHEM + tid * 8;
        float npos = o[0], spos = o[1], spos2 = o[2], nnegt = o[3], sneg2t = o[4];
        float nneg = fminf(3.f * npos, nnegt);
        float ssel;
        if (nneg >= nnegt) ssel = sneg2t;       // all negatives selected (exact path)
        else {
            const float* hc = ws + WS_HCNT + tid * NBINS;
            const float* hs = ws + WS_HS2  + tid * NBINS;
            float acc = 0.f; ssel = 0.f;
            for (int i = NBINS - 1; i >= 0; i--) {
                float c = hc[i];
                if (c <= 0.f) continue;
                if (acc + c <= nneg) { ssel += hs[i]; acc += c; }
                else { float r = nneg - acc; ssel += r * (hs[i] / c); break; }
            }
        }
        float uni = spos2 + ssel + npos + 1e-6f;
        s_text[tid] = 1.f - 2.f * spos / uni;

        float nf  = ws[WS_MISC + tid * 4 + 0];
        float act = ws[WS_MISC + tid * 4 + 3];
        float lv = 0.f;
        for (int l = 0; l < LL; l++) {
            float c = ws[WS_ECNT + tid * LL + l];
            if (c > 0.f) lv += ws[WS_ECV + tid * LL + l] / fmaxf(c, 1.f);
        }
        s_lv[tid] = act * lv / fmaxf(nf, 1.f);
        s_ld[tid] = ws[WS_MISC + tid * 4 + 1];
        s_lr[tid] = ws[WS_MISC + tid * 4 + 2];
    }
    if (tid < 40) {
        const float* kk = ws + WS_KERN + tid * 3;
        s_kern[tid] = 1.f - 2.f * kk[0] / (kk[1] + kk[2] + 1e-6f);
    }
    __syncthreads();
    if (tid == 0) {
        float lt = 0.f; for (int i = 0; i < BB; i++) lt += s_text[i]; lt /= (float)BB;
        float lk = 0.f; for (int i = 0; i < 40; i++) lk += s_kern[i]; lk /= 40.f;
        float lvs = 0.f, lds_ = 0.f, lrs = 0.f;
        for (int i = 0; i < BB; i++) { lvs += s_lv[i]; lds_ += s_ld[i]; lrs += s_lr[i]; }
        float lemb = 0.25f * (lvs + lds_ + 0.001f * (lrs / (float)BB));
        out[0] = lk + 0.5f * lt + lemb;
        out[1] = lt;
        out[2] = lk;
        out[3] = lemb;
    }
}

extern "C" void kernel_launch(void* const* d_in, const int* in_sizes, int n_in,
                              void* d_out, int out_size, void* d_ws, size_t ws_size,
                              hipStream_t stream)
{
    (void)in_sizes; (void)n_in; (void)out_size; (void)ws_size;
    const float* pred = (const float*)d_in[0];
    const float* gt_t = (const float*)d_in[1];
    const float* gtk  = (const float*)d_in[2];
    const float* tm   = (const float*)d_in[3];
    const int*   inst = (const int*)d_in[4];
    float* out = (float*)d_out;
    float* ws  = (float*)d_ws;

    hipMemsetAsync(d_ws, 0, WS_ZERO_END * sizeof(float), stream);

    dim3 g1(WW / 32, HH / 32, BB), b1(32, 8, 1);
    k_dil_stats<<<g1, b1, 0, stream>>>(pred, gt_t, tm, ws);
    k_kern_dice<<<dim3(32, 40), 256, 0, stream>>>(pred, gtk, tm, ws);
    k_emb1<<<dim3(64, BB), 256, 0, stream>>>(pred, inst, tm, ws);
    k_emb_means<<<BB, 128, 0, stream>>>(ws);
    k_emb2<<<dim3(64, BB), 256, 0, stream>>>(pred, inst, tm, ws);
    k_final<<<1, 64, 0, stream>>>(ws, out);
}